// Round 2
// baseline (18705.717 us; speedup 1.0000x reference)
//
#include <hip/hip_runtime.h>

#define E 256
#define KSMP 128

typedef float f32x4 __attribute__((ext_vector_type(4)));

__device__ __forceinline__ unsigned pack_fp8x4(float a, float b, float c, float d) {
    int v = __builtin_amdgcn_cvt_pk_fp8_f32(a, b, 0, false);
    v = __builtin_amdgcn_cvt_pk_fp8_f32(c, d, v, true);
    return (unsigned)v;
}

__device__ __forceinline__ unsigned pack_bf16x2(float a, float b) {
    unsigned r;
    asm("v_cvt_pk_bf16_f32 %0, %1, %2" : "=v"(r) : "v"(a), "v"(b));
    return r;
}

__device__ __forceinline__ void unpack_bf16x2(unsigned u, float& a, float& b) {
    union { unsigned u; float f; } x, y;
    x.u = u << 16; y.u = u & 0xffff0000u;
    a = x.f; b = y.f;
}

// acc[fot] += A(weights from LDS) * B(activation quads via cross-lane permute)
__device__ __forceinline__ void mm_fp8(f32x4 (&acc)[16], const unsigned char* abase,
                                       const unsigned (&q)[16], int addrB0, int addrB1,
                                       bool lowhalf) {
    #pragma unroll
    for (int kc = 0; kc < 8; ++kc) {
        int t00 = __builtin_amdgcn_ds_bpermute(addrB0, (int)q[2*kc]);
        int t01 = __builtin_amdgcn_ds_bpermute(addrB0, (int)q[2*kc+1]);
        int t10 = __builtin_amdgcn_ds_bpermute(addrB1, (int)q[2*kc]);
        int t11 = __builtin_amdgcn_ds_bpermute(addrB1, (int)q[2*kc+1]);
        unsigned b0 = lowhalf ? (unsigned)t00 : (unsigned)t01;
        unsigned b1 = lowhalf ? (unsigned)t10 : (unsigned)t11;
        long B = (long)(((unsigned long long)b1 << 32) | (unsigned long long)b0);
        #pragma unroll
        for (int fot = 0; fot < 16; ++fot) {
            long A = *(const long*)(abase + kc*8192 + fot*128);
            acc[fot] = __builtin_amdgcn_mfma_f32_16x16x32_fp8_fp8(A, B, acc[fot], 0, 0, 0);
        }
    }
}

__global__ __launch_bounds__(512, 2) void cnf_kernel(
    const float* __restrict__ h, const float* __restrict__ emb, const int* __restrict__ tgts,
    const float* __restrict__ Wx, const float* __restrict__ wx_t, const float* __restrict__ bx,
    const float* __restrict__ Wh, const float* __restrict__ wh_t, const float* __restrict__ bh,
    const float* __restrict__ W2, const float* __restrict__ b2, float* __restrict__ out)
{
    // weights, fp8, layout [kchunk c=k/8][f][k%8]  (A-operand ready)
    __shared__ __align__(16) unsigned char lds_wx[65536];
    __shared__ __align__(16) unsigned char lds_w2[65536];
    __shared__ __align__(16) float lds_h[E];
    __shared__ __align__(16) float lds_ht[E];   // h@Wh^T + bx + bh (per-block: one n)
    __shared__ __align__(16) float lds_wt[E];   // wx_t + wh_t
    __shared__ __align__(16) float lds_d[E];    // trace diag: d[f] = sum_i W2[i][f]*Wx[f][i]
    __shared__ __align__(16) float lds_b2[E];

    const int tid = threadIdx.x;
    const int n   = blockIdx.x;
    const int l   = tid & 63;
    const int w   = tid >> 6;
    const int lg  = l >> 4;
    const int lm  = l & 15;

    // ---------- phase 0: small vectors ----------
    if (tid < 64) ((f32x4*)lds_h)[tid] = ((const f32x4*)(h + n*E))[tid];
    if (tid < 256) { lds_wt[tid] = wx_t[tid] + wh_t[tid]; lds_b2[tid] = b2[tid]; }
    __syncthreads();

    // ---------- phase 1: ht/d (threads 0-255) + fp8 weight staging (threads 256-511) ----------
    if (tid < 256) {
        const int f = tid;
        const float* whr = Wh + f*E;
        const float* wxr = Wx + f*E;
        float acch = 0.f, accd = 0.f;
        #pragma unroll 4
        for (int i = 0; i < E; ++i) {
            acch += whr[i] * lds_h[i];
            accd += W2[i*E + f] * wxr[i];
        }
        lds_ht[f] = acch + bx[f] + bh[f];
        lds_d[f]  = accd;
    } else {
        const int f = tid - 256;
        const float* wxr = Wx + f*E;
        const float* w2r = W2 + f*E;
        #pragma unroll 2
        for (int c = 0; c < 32; ++c) {
            f32x4 a = *(const f32x4*)(wxr + c*8);
            f32x4 b = *(const f32x4*)(wxr + c*8 + 4);
            unsigned w0 = pack_fp8x4(a[0], a[1], a[2], a[3]);
            unsigned w1 = pack_fp8x4(b[0], b[1], b[2], b[3]);
            *(unsigned long long*)(lds_wx + (c*256 + f)*8) =
                ((unsigned long long)w1 << 32) | w0;
            a = *(const f32x4*)(w2r + c*8);
            b = *(const f32x4*)(w2r + c*8 + 4);
            w0 = pack_fp8x4(a[0], a[1], a[2], a[3]);
            w1 = pack_fp8x4(b[0], b[1], b[2], b[3]);
            *(unsigned long long*)(lds_w2 + (c*256 + f)*8) =
                ((unsigned long long)w1 << 32) | w0;
        }
    }
    __syncthreads();
    // After this point: no barriers, waves fully independent.

    // ---------- z0 gather + log p(z0) ----------
    // Per-lane state (arch VGPRs, packed to avoid the 128-reg spill cliff):
    //   zp[32]: z as bf16x2 pairs; sp_[32]: RK4 weighted k-sum as bf16x2; qx[16]: fp8 quads.
    unsigned zp[32], sp_[32], qx[16];
    const int sOut = n*KSMP + (w << 4) + lm;
    const int tgt  = tgts[sOut];
    const float* z0p = emb + (size_t)tgt * E;
    float ssq = 0.f;
    #pragma unroll
    for (int ft = 0; ft < 16; ++ft) {
        const int f0 = ft*16 + lg*4;
        f32x4 z = *(const f32x4*)(z0p + f0);
        f32x4 hv = *(const f32x4*)(lds_h + f0);
        #pragma unroll
        for (int r = 0; r < 4; ++r) { float dd = z[r] - hv[r]; ssq += dd*dd; }
        zp[2*ft]   = pack_bf16x2(z[0], z[1]);
        zp[2*ft+1] = pack_bf16x2(z[2], z[3]);
        qx[ft] = pack_fp8x4(z[0], z[1], z[2], z[3]);
    }
    ssq += __shfl_xor(ssq, 16);
    ssq += __shfl_xor(ssq, 32);
    const float lp0 = -0.5f*ssq - 235.2482645f;   // (E/2)*ln(2*pi)

    // cross-lane permute addresses for C-layout quads -> B-operand
    const int addrB0 = 4 * (lm + 16*((2*lg) & 3));
    const int addrB1 = 4 * (lm + 16*((2*lg + 1) & 3));
    const unsigned char* wxbase = lds_wx + (lg*256 + lm)*8;
    const unsigned char* w2base = lds_w2 + (lg*256 + lm)*8;
    const bool lowhalf = (lg < 2);

    const float dt = 0.125f;
    float lpacc = 0.f;

    #pragma unroll 1
    for (int step = 0; step < 8; ++step) {
        const float t0 = step * dt;
        #pragma unroll 1
        for (int e = 0; e < 4; ++e) {
            const float te = t0 + ((e == 0) ? 0.f : (e == 3) ? dt : 0.5f*dt);
            f32x4 acc[16];
            #pragma unroll
            for (int i = 0; i < 16; ++i) acc[i] = (f32x4){0.f, 0.f, 0.f, 0.f};
            mm_fp8(acc, wxbase, qx, addrB0, addrB1, lowhalf);   // pre' = Wx * zs^T

            float trp = 0.f;
            #pragma unroll
            for (int ft = 0; ft < 16; ++ft) {
                const int f0 = ft*16 + lg*4;
                f32x4 htq = *(const f32x4*)(lds_ht + f0);
                f32x4 wtq = *(const f32x4*)(lds_wt + f0);
                f32x4 dq  = *(const f32x4*)(lds_d + f0);
                float sp[4];
                #pragma unroll
                for (int r = 0; r < 4; ++r) {
                    float x  = acc[ft][r] + htq[r] + te*wtq[r];
                    float ee = __builtin_amdgcn_exp2f(fabsf(x) * -1.442695041f); // e^{-|x|}
                    // ln(1+t), t in (0,1]: A&S 4.1.43, |err|<=1e-5
                    float lg1p = ee*(0.99949556f + ee*(-0.49190896f + ee*(0.28947478f +
                                 ee*(-0.13606275f + ee*0.03215845f))));
                    sp[r] = fmaxf(x, 0.f) + lg1p;                 // softplus
                    float rr = __builtin_amdgcn_rcpf(1.f + ee);
                    float sg = (x >= 0.f) ? rr : 1.f - rr;        // sigmoid
                    trp += sg * dq[r];
                }
                qx[ft] = pack_fp8x4(sp[0], sp[1], sp[2], sp[3]);
            }

            #pragma unroll
            for (int i = 0; i < 16; ++i) acc[i] = (f32x4){0.f, 0.f, 0.f, 0.f};
            mm_fp8(acc, w2base, qx, addrB0, addrB1, lowhalf);    // dz' = W2 * softplus^T

            const float we = (e == 0 || e == 3) ? 1.f : 2.f;
            lpacc += we * trp;
            const float ce = (e == 2) ? dt : 0.5f*dt;
            #pragma unroll
            for (int ft = 0; ft < 16; ++ft) {
                const int f0 = ft*16 + lg*4;
                f32x4 b2q = *(const f32x4*)(lds_b2 + f0);
                float z4[4];
                #pragma unroll
                for (int hf = 0; hf < 2; ++hf) {
                    const int r0 = 2*hf, r1 = 2*hf + 1;
                    float k0 = acc[ft][r0] + b2q[r0];
                    float k1 = acc[ft][r1] + b2q[r1];
                    // weighted RK4 sum s += we*k (bf16x2 packed)
                    if (e == 0) {
                        sp_[2*ft+hf] = pack_bf16x2(k0, k1);
                    } else {
                        float s0, s1; unpack_bf16x2(sp_[2*ft+hf], s0, s1);
                        sp_[2*ft+hf] = pack_bf16x2(s0 + we*k0, s1 + we*k1);
                    }
                    float z0, z1; unpack_bf16x2(zp[2*ft+hf], z0, z1);
                    if (e < 3) {
                        z4[r0] = z0 + ce*k0;
                        z4[r1] = z1 + ce*k1;
                    } else {
                        float s0, s1; unpack_bf16x2(sp_[2*ft+hf], s0, s1);
                        z4[r0] = z0 + (dt/6.f)*s0;
                        z4[r1] = z1 + (dt/6.f)*s1;
                        zp[2*ft+hf] = pack_bf16x2(z4[r0], z4[r1]);
                    }
                }
                qx[ft] = pack_fp8x4(z4[0], z4[1], z4[2], z4[3]);
            }
        }
    }

    float lptot = lpacc;
    lptot += __shfl_xor(lptot, 16);
    lptot += __shfl_xor(lptot, 32);
    const float res = lp0 - (dt/6.f)*lptot;
    if (l < 16) out[sOut] = res;
}

extern "C" void kernel_launch(void* const* d_in, const int* in_sizes, int n_in,
                              void* d_out, int out_size, void* d_ws, size_t ws_size,
                              hipStream_t stream) {
    const float* h    = (const float*)d_in[0];
    const float* emb  = (const float*)d_in[1];
    const int*   tg   = (const int*)d_in[2];
    const float* Wx   = (const float*)d_in[3];
    const float* wx_t = (const float*)d_in[4];
    const float* bx   = (const float*)d_in[5];
    const float* wh_t = (const float*)d_in[6] ? (const float*)d_in[7] : (const float*)d_in[7];
    const float* Wh   = (const float*)d_in[6];
    const float* bh   = (const float*)d_in[8];
    const float* W2   = (const float*)d_in[9];
    const float* b2   = (const float*)d_in[10];
    cnf_kernel<<<dim3(512), dim3(512), 0, stream>>>(h, emb, tg, Wx, wx_t, bx, Wh, wh_t, bh,
                                                    W2, b2, (float*)d_out);
}

// Round 3
// 790.540 us; speedup vs baseline: 23.6619x; 23.6619x over previous
//
#include <hip/hip_runtime.h>

#define E 256

typedef float f32x4 __attribute__((ext_vector_type(4)));
typedef unsigned int u32;
typedef unsigned long long u64;

// ws layout (bytes):
//   [0      , 65536 )  Wx fp8, [c=k/8][f][8B]   (MFMA A-operand-ready)
//   [65536  , 131072)  W2 fp8, [c][f][8B]
//   [131072 , 132096)  d   (256 f32)  d[f] = sum_i W2[i][f]*Wx[f][i]
//   [132096 , 133120)  wt  (256 f32)  wx_t + wh_t
//   [133120 , 134144)  b2  (256 f32)
//   [134144 , 134144+512*1024)  ht[n][f] (512 x 256 f32) = h@Wh^T + bx + bh
#define WS_W2 65536
#define WS_D  131072
#define WS_WT 132096
#define WS_B2 133120
#define WS_HT 134144

__device__ __forceinline__ u32 pack_fp8x4(float a, float b, float c, float d) {
    int v = __builtin_amdgcn_cvt_pk_fp8_f32(a, b, 0, false);
    v = __builtin_amdgcn_cvt_pk_fp8_f32(c, d, v, true);
    return (u32)v;
}

__global__ __launch_bounds__(256) void prep_kernel(
    const float* __restrict__ h,
    const float* __restrict__ Wx, const float* __restrict__ wx_t, const float* __restrict__ bx,
    const float* __restrict__ Wh, const float* __restrict__ wh_t, const float* __restrict__ bh,
    const float* __restrict__ W2, const float* __restrict__ b2,
    unsigned char* __restrict__ ws)
{
    __shared__ float sh[2][E];
    const int b = blockIdx.x;       // 256 blocks; block b -> ht rows 2b, 2b+1
    const int f = threadIdx.x;      // 256 threads: one feature each
    sh[0][f] = h[(2*b)*E + f];
    sh[1][f] = h[(2*b+1)*E + f];
    __syncthreads();

    const float* whr = Wh + f*E;
    float a0 = 0.f, a1 = 0.f;
    #pragma unroll 4
    for (int i = 0; i < E; ++i) {
        float wv = whr[i];
        a0 += wv * sh[0][i];
        a1 += wv * sh[1][i];
    }
    const float bb = bx[f] + bh[f];
    float* ht = (float*)(ws + WS_HT);
    ht[(2*b)*E + f]   = a0 + bb;
    ht[(2*b+1)*E + f] = a1 + bb;

    if (b == 0) {
        const float* wxr = Wx + f*E;
        const float* w2r = W2 + f*E;
        float accd = 0.f;
        #pragma unroll 4
        for (int i = 0; i < E; ++i) accd += W2[i*E + f] * wxr[i];   // W2 col f (coalesced across threads)
        ((float*)(ws + WS_D))[f]  = accd;
        ((float*)(ws + WS_WT))[f] = wx_t[f] + wh_t[f];
        ((float*)(ws + WS_B2))[f] = b2[f];
        #pragma unroll 2
        for (int c = 0; c < 32; ++c) {
            f32x4 x0 = *(const f32x4*)(wxr + c*8);
            f32x4 x1 = *(const f32x4*)(wxr + c*8 + 4);
            u64 p = ((u64)pack_fp8x4(x1[0],x1[1],x1[2],x1[3]) << 32) |
                     (u64)pack_fp8x4(x0[0],x0[1],x0[2],x0[3]);
            *(u64*)(ws + (c*256 + f)*8) = p;
            x0 = *(const f32x4*)(w2r + c*8);
            x1 = *(const f32x4*)(w2r + c*8 + 4);
            p = ((u64)pack_fp8x4(x1[0],x1[1],x1[2],x1[3]) << 32) |
                (u64)pack_fp8x4(x0[0],x0[1],x0[2],x0[3]);
            *(u64*)(ws + WS_W2 + (c*256 + f)*8) = p;
        }
    }
}

// 2048 blocks x 512 thr. Block: 32 samples = 2 groups x 16; group = 4 waves,
// wave wg owns features [wg*64, wg*64+64). Activations exchanged via swizzled
// fp8 LDS buffers; 2 barriers per eval. Per-lane state ~100 VGPRs (no spill).
__global__ __launch_bounds__(512, 2) void cnf_main(
    const float* __restrict__ hmat, const float* __restrict__ emb,
    const int* __restrict__ tgts, const unsigned char* __restrict__ ws,
    float* __restrict__ out)
{
    __shared__ __align__(16) unsigned char lwx[65536];
    __shared__ __align__(16) unsigned char lw2[65536];
    __shared__ __align__(16) float lh[E], lht[E], lwt[E], ld_[E], lb2[E];
    __shared__ __align__(16) unsigned char actA[2][4096];   // z-stage fp8, [s][f^swz]
    __shared__ __align__(16) unsigned char actB[2][4096];   // softplus fp8
    __shared__ float red[2][4][16];

    const int tid = threadIdx.x;
    const int bId = blockIdx.x;
    const int n   = bId >> 2;           // 4 blocks per h-row

    // ---- prologue: coalesced copy of prepped data ----
    #pragma unroll
    for (int k = 0; k < 8; ++k) {
        ((uint4*)lwx)[tid + k*512] = ((const uint4*)(ws))[tid + k*512];
        ((uint4*)lw2)[tid + k*512] = ((const uint4*)(ws + WS_W2))[tid + k*512];
    }
    if (tid < 256) {
        ld_[tid] = ((const float*)(ws + WS_D))[tid];
        lwt[tid] = ((const float*)(ws + WS_WT))[tid];
        lb2[tid] = ((const float*)(ws + WS_B2))[tid];
        lht[tid] = ((const float*)(ws + WS_HT + n*1024))[tid];
        lh[tid]  = hmat[n*E + tid];
    }
    __syncthreads();

    const int l  = tid & 63, wv = tid >> 6;
    const int g  = wv >> 2, wg = wv & 3;
    const int lm = l & 15,  lg = l >> 4;
    const int fbase = wg * 64;
    const int sOwn  = bId*32 + g*16 + lm;
    unsigned char* aA = actA[g];
    unsigned char* aB = actB[g];
    const int swz = (lm & 7) << 3;      // XOR-swizzle: byte bits 3-5 by sample

    // ---- z0 gather, log p(z0) partial, initial z write ----
    const int tgt = tgts[sOwn];
    const float* z0p = emb + (size_t)tgt * E;
    f32x4 zb[4];
    float ssq = 0.f;
    #pragma unroll
    for (int ft = 0; ft < 4; ++ft) {
        const int f0 = fbase + ft*16 + lg*4;
        f32x4 z = *(const f32x4*)(z0p + f0);
        zb[ft] = z;
        f32x4 hv = *(const f32x4*)(lh + f0);
        #pragma unroll
        for (int r = 0; r < 4; ++r) { float dd = z[r] - hv[r]; ssq += dd*dd; }
        *(u32*)(aA + lm*256 + (f0 ^ swz)) = pack_fp8x4(z[0], z[1], z[2], z[3]);
    }
    ssq += __shfl_xor(ssq, 16);
    ssq += __shfl_xor(ssq, 32);
    if (l < 16) red[g][wg][lm] = ssq;
    __syncthreads();                      // z0 + ssq partials visible
    const float lp0 = -0.5f*(red[g][0][lm] + red[g][1][lm] + red[g][2][lm] + red[g][3][lm])
                      - 235.2482645f;     // (E/2)*ln(2*pi)

    const float dt = 0.125f;
    float lpacc = 0.f;
    f32x4 sacc[4];

    #pragma unroll 1
    for (int e = 0; e < 32; ++e) {
        const int sub = e & 3;
        const float te = (float)(e >> 2) * dt +
                         ((sub == 0) ? 0.f : (sub == 3) ? dt : 0.5f*dt);
        // ---- mm1: pre-slice = Wx[fbase..+64, :] @ z ----
        f32x4 acc[4];
        #pragma unroll
        for (int i = 0; i < 4; ++i) acc[i] = (f32x4){0.f,0.f,0.f,0.f};
        #pragma unroll
        for (int kc = 0; kc < 8; ++kc) {
            long Bf = *(const long*)(aA + lm*256 + ((kc*32 + lg*8) ^ swz));
            #pragma unroll
            for (int fot = 0; fot < 4; ++fot) {
                long Af = *(const long*)(lwx + ((kc*4 + lg)*256 + fbase + fot*16 + lm)*8);
                acc[fot] = __builtin_amdgcn_mfma_f32_16x16x32_fp8_fp8(Af, Bf, acc[fot], 0,0,0);
            }
        }
        // ---- softplus + sigmoid-trace, write sp to actB ----
        float trp = 0.f;
        #pragma unroll
        for (int ft = 0; ft < 4; ++ft) {
            const int f0 = fbase + ft*16 + lg*4;
            f32x4 htq = *(const f32x4*)(lht + f0);
            f32x4 wtq = *(const f32x4*)(lwt + f0);
            f32x4 dq  = *(const f32x4*)(ld_ + f0);
            float sp[4];
            #pragma unroll
            for (int r = 0; r < 4; ++r) {
                float x  = acc[ft][r] + htq[r] + te*wtq[r];
                float ee = __builtin_amdgcn_exp2f(fabsf(x) * -1.442695041f); // e^{-|x|}
                float lg1p = ee*(0.99949556f + ee*(-0.49190896f + ee*(0.28947478f +
                             ee*(-0.13606275f + ee*0.03215845f))));          // ln(1+ee)
                sp[r] = fmaxf(x, 0.f) + lg1p;
                float rr = __builtin_amdgcn_rcpf(1.f + ee);
                float sg = (x >= 0.f) ? rr : 1.f - rr;
                trp += sg * dq[r];
            }
            *(u32*)(aB + lm*256 + (f0 ^ swz)) = pack_fp8x4(sp[0], sp[1], sp[2], sp[3]);
        }
        __syncthreads();                  // actB ready; actA free to overwrite
        // ---- mm2: k-slice = W2[fbase..+64, :] @ softplus ----
        f32x4 acc2[4];
        #pragma unroll
        for (int i = 0; i < 4; ++i) acc2[i] = (f32x4){0.f,0.f,0.f,0.f};
        #pragma unroll
        for (int kc = 0; kc < 8; ++kc) {
            long Bf = *(const long*)(aB + lm*256 + ((kc*32 + lg*8) ^ swz));
            #pragma unroll
            for (int fot = 0; fot < 4; ++fot) {
                long Af = *(const long*)(lw2 + ((kc*4 + lg)*256 + fbase + fot*16 + lm)*8);
                acc2[fot] = __builtin_amdgcn_mfma_f32_16x16x32_fp8_fp8(Af, Bf, acc2[fot], 0,0,0);
            }
        }
        // ---- RK4 state update, write next z-stage to actA ----
        const float we = (sub == 0 || sub == 3) ? 1.f : 2.f;
        lpacc += we * trp;
        const float ce = (sub == 2) ? dt : 0.5f*dt;
        #pragma unroll
        for (int ft = 0; ft < 4; ++ft) {
            const int f0 = fbase + ft*16 + lg*4;
            f32x4 b2q = *(const f32x4*)(lb2 + f0);
            float z4[4];
            #pragma unroll
            for (int r = 0; r < 4; ++r) {
                float kk = acc2[ft][r] + b2q[r];
                if (sub == 0) sacc[ft][r] = kk; else sacc[ft][r] += we*kk;
                if (sub < 3) {
                    z4[r] = zb[ft][r] + ce*kk;
                } else {
                    zb[ft][r] += (dt/6.f)*sacc[ft][r];
                    z4[r] = zb[ft][r];
                }
            }
            *(u32*)(aA + lm*256 + (f0 ^ swz)) = pack_fp8x4(z4[0], z4[1], z4[2], z4[3]);
        }
        __syncthreads();                  // next z-stage visible to all waves
    }

    // ---- final reduction: trace over features (4 waves) ----
    lpacc += __shfl_xor(lpacc, 16);
    lpacc += __shfl_xor(lpacc, 32);
    if (l < 16) red[g][wg][lm] = lpacc;
    __syncthreads();
    if (wg == 0 && l < 16) {
        float lt = red[g][0][lm] + red[g][1][lm] + red[g][2][lm] + red[g][3][lm];
        out[sOwn] = lp0 - (dt/6.f)*lt;
    }
}

extern "C" void kernel_launch(void* const* d_in, const int* in_sizes, int n_in,
                              void* d_out, int out_size, void* d_ws, size_t ws_size,
                              hipStream_t stream) {
    const float* h    = (const float*)d_in[0];
    const float* emb  = (const float*)d_in[1];
    const int*   tg   = (const int*)d_in[2];
    const float* Wx   = (const float*)d_in[3];
    const float* wx_t = (const float*)d_in[4];
    const float* bx   = (const float*)d_in[5];
    const float* Wh   = (const float*)d_in[6];
    const float* wh_t = (const float*)d_in[7];
    const float* bh   = (const float*)d_in[8];
    const float* W2   = (const float*)d_in[9];
    const float* b2   = (const float*)d_in[10];
    unsigned char* ws = (unsigned char*)d_ws;

    prep_kernel<<<dim3(256), dim3(256), 0, stream>>>(h, Wx, wx_t, bx, Wh, wh_t, bh, W2, b2, ws);
    cnf_main<<<dim3(2048), dim3(512), 0, stream>>>(h, emb, tg, ws, (float*)d_out);
}

// Round 4
// 639.532 us; speedup vs baseline: 29.2491x; 1.2361x over previous
//
#include <hip/hip_runtime.h>

#define E 256

typedef float f32x4 __attribute__((ext_vector_type(4)));
typedef unsigned int u32;
typedef unsigned long long u64;

// ws layout (bytes):
//   [0      , 65536 )  Wx fp8, [c=k/8][f][8B]   (MFMA A-operand-ready)
//   [65536  , 131072)  W2 fp8, [c][f][8B]
//   [131072 , 132096)  d   (256 f32)
//   [132096 , 133120)  wt  (256 f32)
//   [133120 , 134144)  b2  (256 f32)
//   [134144 , +512KB)  ht[n][f] (512 x 256 f32) = h@Wh^T + bx + bh
#define WS_W2 65536
#define WS_D  131072
#define WS_WT 132096
#define WS_B2 133120
#define WS_HT 134144

__device__ __forceinline__ u32 pack_fp8x4(float a, float b, float c, float d) {
    int v = __builtin_amdgcn_cvt_pk_fp8_f32(a, b, 0, false);
    v = __builtin_amdgcn_cvt_pk_fp8_f32(c, d, v, true);
    return (u32)v;
}

// decode OCP e4m3fn byte -> f32 (LUT build only; NaN clamps to +-448)
__device__ __forceinline__ float fp8_to_f32(int b) {
    int s = (b >> 7) & 1, ex = (b >> 3) & 15, mn = b & 7;
    float v;
    if (ex == 0)            v = (float)mn * 0.001953125f;        // mn * 2^-9
    else if (ex == 15 && mn == 7) v = 448.f;
    else                    v = (1.f + (float)mn * 0.125f) * exp2f((float)(ex - 7));
    return s ? -v : v;
}

__global__ __launch_bounds__(256) void prep_kernel(
    const float* __restrict__ h,
    const float* __restrict__ Wx, const float* __restrict__ wx_t, const float* __restrict__ bx,
    const float* __restrict__ Wh, const float* __restrict__ wh_t, const float* __restrict__ bh,
    const float* __restrict__ W2, const float* __restrict__ b2,
    unsigned char* __restrict__ ws)
{
    __shared__ float sh[2][E];
    const int b = blockIdx.x;
    const int f = threadIdx.x;
    sh[0][f] = h[(2*b)*E + f];
    sh[1][f] = h[(2*b+1)*E + f];
    __syncthreads();

    const float* whr = Wh + f*E;
    float a0 = 0.f, a1 = 0.f;
    #pragma unroll 4
    for (int i = 0; i < E; ++i) {
        float wv = whr[i];
        a0 += wv * sh[0][i];
        a1 += wv * sh[1][i];
    }
    const float bb = bx[f] + bh[f];
    float* ht = (float*)(ws + WS_HT);
    ht[(2*b)*E + f]   = a0 + bb;
    ht[(2*b+1)*E + f] = a1 + bb;

    if (b == 0) {
        const float* wxr = Wx + f*E;
        const float* w2r = W2 + f*E;
        float accd = 0.f;
        #pragma unroll 4
        for (int i = 0; i < E; ++i) accd += W2[i*E + f] * wxr[i];
        ((float*)(ws + WS_D))[f]  = accd;
        ((float*)(ws + WS_WT))[f] = wx_t[f] + wh_t[f];
        ((float*)(ws + WS_B2))[f] = b2[f];
        #pragma unroll 2
        for (int c = 0; c < 32; ++c) {
            f32x4 x0 = *(const f32x4*)(wxr + c*8);
            f32x4 x1 = *(const f32x4*)(wxr + c*8 + 4);
            u64 p = ((u64)pack_fp8x4(x1[0],x1[1],x1[2],x1[3]) << 32) |
                     (u64)pack_fp8x4(x0[0],x0[1],x0[2],x0[3]);
            *(u64*)(ws + (c*256 + f)*8) = p;
            x0 = *(const f32x4*)(w2r + c*8);
            x1 = *(const f32x4*)(w2r + c*8 + 4);
            p = ((u64)pack_fp8x4(x1[0],x1[1],x1[2],x1[3]) << 32) |
                (u64)pack_fp8x4(x0[0],x0[1],x0[2],x0[3]);
            *(u64*)(ws + WS_W2 + (c*256 + f)*8) = p;
        }
    }
}

// 2048 blocks x 512 thr; 2 groups x 4 waves x 16 samples; wave owns 64 features.
// Weight A-fragments resident in VGPRs (no weight LDS). Activation via fp8 LUT.
__global__ __launch_bounds__(512, 2) void cnf_main(
    const float* __restrict__ hmat, const float* __restrict__ emb,
    const int* __restrict__ tgts, const unsigned char* __restrict__ ws,
    float* __restrict__ out)
{
    __shared__ __align__(16) float lh[E], lht[E], lwt[E], ld_[E], lb2[E];
    __shared__ __align__(16) u32 lut[256];          // sg_bf16<<16 | sp_fp8
    __shared__ __align__(16) unsigned char act[2][2][4096]; // [group][z/sp][rotated]
    __shared__ float red[2][4][16];

    const int tid = threadIdx.x;
    const int bId = blockIdx.x;
    const int n   = bId >> 2;

    const int l  = tid & 63, wv = tid >> 6;
    const int g  = wv >> 2, wg = wv & 3;
    const int lm = l & 15,  lg = l >> 4;
    const int fbase = wg * 64;

    // ---- weight fragments -> registers (global, L2-served, one-time) ----
    long awx[32], aw2[32];
    #pragma unroll
    for (int kc = 0; kc < 8; ++kc) {
        #pragma unroll
        for (int fot = 0; fot < 4; ++fot) {
            const size_t off = (size_t)(((kc*4 + lg)*256) + fbase + fot*16 + lm) * 8;
            awx[kc*4+fot] = *(const long*)(ws + off);
            aw2[kc*4+fot] = *(const long*)(ws + WS_W2 + off);
        }
    }

    // ---- prologue: vectors + LUT ----
    if (tid < 256) {
        ld_[tid] = ((const float*)(ws + WS_D))[tid];
        lwt[tid] = ((const float*)(ws + WS_WT))[tid];
        lb2[tid] = ((const float*)(ws + WS_B2))[tid];
        lht[tid] = ((const float*)(ws + WS_HT + n*1024))[tid];
        lh[tid]  = hmat[n*E + tid];
        float x  = fp8_to_f32(tid);
        float ax = fabsf(x);
        float em = expf(-ax);
        float sp = fmaxf(x, 0.f) + log1pf(em);
        float rr = 1.f / (1.f + em);
        float sg = (x >= 0.f) ? rr : 1.f - rr;
        union { float f; u32 u; } su; su.f = sg;
        lut[tid] = (su.u & 0xffff0000u) | (pack_fp8x4(sp, 0.f, 0.f, 0.f) & 0xffu);
    }
    __syncthreads();

    // ---- precomputed LDS addresses (rotate-swizzle: byte (f + 16*lm) & 255) ----
    unsigned char* aZ = &act[g][0][0];
    unsigned char* aS = &act[g][1][0];
    int addrB[8], addrW[4];
    #pragma unroll
    for (int kc = 0; kc < 8; ++kc)
        addrB[kc] = lm*256 + ((kc*32 + lg*8 + lm*16) & 255);
    #pragma unroll
    for (int ft = 0; ft < 4; ++ft)
        addrW[ft] = lm*256 + ((fbase + ft*16 + lg*4 + lm*16) & 255);

    // ---- z0 gather, log p(z0), initial z-stage ----
    const int sOwn = bId*32 + g*16 + lm;
    const int tgt  = tgts[sOwn];
    const float* z0p = emb + (size_t)tgt * E;
    f32x4 zb[4], sacc[4];
    float ssq = 0.f;
    #pragma unroll
    for (int ft = 0; ft < 4; ++ft) {
        const int f0 = fbase + ft*16 + lg*4;
        f32x4 z = *(const f32x4*)(z0p + f0);
        zb[ft] = z;
        f32x4 hv = *(const f32x4*)(lh + f0);
        #pragma unroll
        for (int r = 0; r < 4; ++r) { float dd = z[r] - hv[r]; ssq += dd*dd; }
        *(u32*)(aZ + addrW[ft]) = pack_fp8x4(z[0], z[1], z[2], z[3]);
    }
    ssq += __shfl_xor(ssq, 16);
    ssq += __shfl_xor(ssq, 32);
    if (l < 16) red[g][wg][lm] = ssq;
    __syncthreads();
    const float lp0 = -0.5f*(red[g][0][lm] + red[g][1][lm] + red[g][2][lm] + red[g][3][lm])
                      - 235.2482645f;

    const float dt = 0.125f;
    float lpacc = 0.f;

    #pragma unroll 1
    for (int e = 0; e < 32; ++e) {
        const int sub = e & 3;
        const float te = (float)(e >> 2) * dt +
                         ((sub == 0) ? 0.f : (sub == 3) ? dt : 0.5f*dt);
        // ---- mm1: pre-slice = Wx[fbase..+64, :] @ z ----
        f32x4 acc[4];
        #pragma unroll
        for (int i = 0; i < 4; ++i) acc[i] = (f32x4){0.f,0.f,0.f,0.f};
        #pragma unroll
        for (int kc = 0; kc < 8; ++kc) {
            long Bf = *(const long*)(aZ + addrB[kc]);
            #pragma unroll
            for (int fot = 0; fot < 4; ++fot)
                acc[fot] = __builtin_amdgcn_mfma_f32_16x16x32_fp8_fp8(awx[kc*4+fot], Bf, acc[fot], 0,0,0);
        }
        // ---- activation via LUT; write sp-fp8 to aS ----
        float trp = 0.f;
        #pragma unroll
        for (int ft = 0; ft < 4; ++ft) {
            const int f0 = fbase + ft*16 + lg*4;
            f32x4 htq = *(const f32x4*)(lht + f0);
            f32x4 wtq = *(const f32x4*)(lwt + f0);
            f32x4 dq  = *(const f32x4*)(ld_ + f0);
            float p0 = acc[ft][0] + htq[0] + te*wtq[0];
            float p1 = acc[ft][1] + htq[1] + te*wtq[1];
            float p2 = acc[ft][2] + htq[2] + te*wtq[2];
            float p3 = acc[ft][3] + htq[3] + te*wtq[3];
            u32 q = pack_fp8x4(p0, p1, p2, p3);
            u32 e0 = lut[q & 255], e1 = lut[(q >> 8) & 255];
            u32 e2 = lut[(q >> 16) & 255], e3 = lut[q >> 24];
            union { u32 u; float f; } s0, s1, s2, s3;
            s0.u = e0 & 0xffff0000u; s1.u = e1 & 0xffff0000u;
            s2.u = e2 & 0xffff0000u; s3.u = e3 & 0xffff0000u;
            trp += s0.f*dq[0] + s1.f*dq[1] + s2.f*dq[2] + s3.f*dq[3];
            u32 t0 = __builtin_amdgcn_perm(e1, e0, 0x00000400u);  // {e0b0,e1b0,-,-}
            u32 t1 = __builtin_amdgcn_perm(e3, e2, 0x00000400u);  // {e2b0,e3b0,-,-}
            *(u32*)(aS + addrW[ft]) = __builtin_amdgcn_perm(t1, t0, 0x05040100u);
        }
        __syncthreads();                  // sp visible
        // ---- mm2: k-slice = W2[fbase..+64, :] @ softplus ----
        f32x4 acc2[4];
        #pragma unroll
        for (int i = 0; i < 4; ++i) acc2[i] = (f32x4){0.f,0.f,0.f,0.f};
        #pragma unroll
        for (int kc = 0; kc < 8; ++kc) {
            long Bf = *(const long*)(aS + addrB[kc]);
            #pragma unroll
            for (int fot = 0; fot < 4; ++fot)
                acc2[fot] = __builtin_amdgcn_mfma_f32_16x16x32_fp8_fp8(aw2[kc*4+fot], Bf, acc2[fot], 0,0,0);
        }
        // ---- RK4 update; write next z-stage to aZ ----
        const float we = (sub == 0 || sub == 3) ? 1.f : 2.f;
        lpacc += we * trp;
        const float ce = (sub == 2) ? dt : 0.5f*dt;
        #pragma unroll
        for (int ft = 0; ft < 4; ++ft) {
            const int f0 = fbase + ft*16 + lg*4;
            f32x4 b2q = *(const f32x4*)(lb2 + f0);
            float z4[4];
            #pragma unroll
            for (int r = 0; r < 4; ++r) {
                float kk = acc2[ft][r] + b2q[r];
                if (sub == 0) sacc[ft][r] = kk; else sacc[ft][r] += we*kk;
                if (sub < 3) {
                    z4[r] = zb[ft][r] + ce*kk;
                } else {
                    zb[ft][r] += (dt/6.f)*sacc[ft][r];
                    z4[r] = zb[ft][r];
                }
            }
            *(u32*)(aZ + addrW[ft]) = pack_fp8x4(z4[0], z4[1], z4[2], z4[3]);
        }
        __syncthreads();                  // next z visible
    }

    // ---- final trace reduction across the 4 feature-waves ----
    lpacc += __shfl_xor(lpacc, 16);
    lpacc += __shfl_xor(lpacc, 32);
    if (l < 16) red[g][wg][lm] = lpacc;
    __syncthreads();
    if (wg == 0 && l < 16) {
        float lt = red[g][0][lm] + red[g][1][lm] + red[g][2][lm] + red[g][3][lm];
        out[sOwn] = lp0 - (dt/6.f)*lt;
    }
}

extern "C" void kernel_launch(void* const* d_in, const int* in_sizes, int n_in,
                              void* d_out, int out_size, void* d_ws, size_t ws_size,
                              hipStream_t stream) {
    const float* h    = (const float*)d_in[0];
    const float* emb  = (const float*)d_in[1];
    const int*   tg   = (const int*)d_in[2];
    const float* Wx   = (const float*)d_in[3];
    const float* wx_t = (const float*)d_in[4];
    const float* bx   = (const float*)d_in[5];
    const float* Wh   = (const float*)d_in[6];
    const float* wh_t = (const float*)d_in[7];
    const float* bh   = (const float*)d_in[8];
    const float* W2   = (const float*)d_in[9];
    const float* b2   = (const float*)d_in[10];
    unsigned char* ws = (unsigned char*)d_ws;

    prep_kernel<<<dim3(256), dim3(256), 0, stream>>>(h, Wx, wx_t, bx, Wh, wh_t, bh, W2, b2, ws);
    cnf_main<<<dim3(2048), dim3(512), 0, stream>>>(h, emb, tg, ws, (float*)d_out);
}

// Round 5
// 503.074 us; speedup vs baseline: 37.1829x; 1.2712x over previous
//
#include <hip/hip_runtime.h>

#define E 256

typedef float f32x4 __attribute__((ext_vector_type(4)));
typedef int   i32x8 __attribute__((ext_vector_type(8)));
typedef unsigned int u32;
typedef unsigned long long u64;

// ws layout (bytes):
//   [0      , 65536 )  Wx fp8 MX-A layout: [kblk(2)][lg(4)][f(256)][32B]
//   [65536  , 131072)  W2 fp8 same layout
//   [131072 , 132096)  d   (256 f32)
//   [132096 , 133120)  wt  (256 f32)
//   [133120 , 134144)  b2  (256 f32)
//   [134144 , +512KB)  ht[n][f] (512 x 256 f32) = h@Wh^T + bx + bh
#define WS_W2 65536
#define WS_D  131072
#define WS_WT 132096
#define WS_B2 133120
#define WS_HT 134144

#define SCL 0x7f7f7f7f   // E8M0 127 = 2^0 in every byte

__device__ __forceinline__ u32 pack_fp8x4(float a, float b, float c, float d) {
    int v = __builtin_amdgcn_cvt_pk_fp8_f32(a, b, 0, false);
    v = __builtin_amdgcn_cvt_pk_fp8_f32(c, d, v, true);
    return (u32)v;
}

// decode OCP e4m3fn byte -> f32 (LUT build only; NaN clamps to +-448)
__device__ __forceinline__ float fp8_to_f32(int b) {
    int s = (b >> 7) & 1, ex = (b >> 3) & 15, mn = b & 7;
    float v;
    if (ex == 0)            v = (float)mn * 0.001953125f;
    else if (ex == 15 && mn == 7) v = 448.f;
    else                    v = (1.f + (float)mn * 0.125f) * exp2f((float)(ex - 7));
    return s ? -v : v;
}

__global__ __launch_bounds__(256) void prep_kernel(
    const float* __restrict__ h,
    const float* __restrict__ Wx, const float* __restrict__ wx_t, const float* __restrict__ bx,
    const float* __restrict__ Wh, const float* __restrict__ wh_t, const float* __restrict__ bh,
    const float* __restrict__ W2, const float* __restrict__ b2,
    unsigned char* __restrict__ ws)
{
    __shared__ float sh[2][E];
    const int b = blockIdx.x;
    const int f = threadIdx.x;
    sh[0][f] = h[(2*b)*E + f];
    sh[1][f] = h[(2*b+1)*E + f];
    __syncthreads();

    const float* whr = Wh + f*E;
    float a0 = 0.f, a1 = 0.f;
    #pragma unroll 4
    for (int i = 0; i < E; ++i) {
        float wv = whr[i];
        a0 += wv * sh[0][i];
        a1 += wv * sh[1][i];
    }
    const float bb = bx[f] + bh[f];
    float* ht = (float*)(ws + WS_HT);
    ht[(2*b)*E + f]   = a0 + bb;
    ht[(2*b+1)*E + f] = a1 + bb;

    if (b == 0) {
        const float* wxr = Wx + f*E;
        const float* w2r = W2 + f*E;
        float accd = 0.f;
        #pragma unroll 4
        for (int i = 0; i < E; ++i) accd += W2[i*E + f] * wxr[i];
        ((float*)(ws + WS_D))[f]  = accd;
        ((float*)(ws + WS_WT))[f] = wx_t[f] + wh_t[f];
        ((float*)(ws + WS_B2))[f] = b2[f];
        // MX A-layout: block (kblk, lgb) holds k = kblk*128 + lgb*32 + 0..31 of row f
        #pragma unroll
        for (int kblk = 0; kblk < 2; ++kblk) {
            #pragma unroll
            for (int lgb = 0; lgb < 4; ++lgb) {
                const int k0 = kblk*128 + lgb*32;
                const size_t off = (size_t)(((kblk*4 + lgb)*256) + f) * 32;
                u32 wq[8], w2q[8];
                #pragma unroll
                for (int j = 0; j < 8; ++j) {
                    f32x4 x = *(const f32x4*)(wxr + k0 + j*4);
                    wq[j]  = pack_fp8x4(x[0], x[1], x[2], x[3]);
                    x = *(const f32x4*)(w2r + k0 + j*4);
                    w2q[j] = pack_fp8x4(x[0], x[1], x[2], x[3]);
                }
                *(uint4*)(ws + off)            = *(uint4*)&wq[0];
                *(uint4*)(ws + off + 16)       = *(uint4*)&wq[4];
                *(uint4*)(ws + WS_W2 + off)    = *(uint4*)&w2q[0];
                *(uint4*)(ws + WS_W2 + off+16) = *(uint4*)&w2q[4];
            }
        }
    }
}

// 2048 blocks x 512 thr; 2 groups x 4 waves x 16 samples; wave owns 64 features.
// Weights resident in (A)GPRs as 16x16x128 MX fragments; activation via fp8 LUT.
__global__ __launch_bounds__(512, 2) void cnf_main(
    const float* __restrict__ hmat, const float* __restrict__ emb,
    const int* __restrict__ tgts, const unsigned char* __restrict__ ws,
    float* __restrict__ out)
{
    __shared__ __align__(16) float lh[E], lht[E], lwt[E], ld_[E], lb2[E];
    __shared__ __align__(16) u32 lut[256];          // sg_bf16<<16 | sp_fp8
    __shared__ __align__(16) unsigned char act[2][2][4096]; // [group][z/sp][rotated]
    __shared__ float red[2][4][16];

    const int tid = threadIdx.x;
    const int bId = blockIdx.x;
    const int n   = bId >> 2;

    const int l  = tid & 63, wv = tid >> 6;
    const int g  = wv >> 2, wg = wv & 3;
    const int lm = l & 15,  lg = l >> 4;
    const int fbase = wg * 64;

    // ---- weight fragments -> registers (one-time, L2-served) ----
    union frag { uint4 q[2]; i32x8 v; };
    frag awx[8], aw2[8];                    // [kblk*4 + fot]
    #pragma unroll
    for (int kblk = 0; kblk < 2; ++kblk) {
        #pragma unroll
        for (int fot = 0; fot < 4; ++fot) {
            const size_t off = (size_t)(((kblk*4 + lg)*256) + fbase + fot*16 + lm) * 32;
            awx[kblk*4+fot].q[0] = *(const uint4*)(ws + off);
            awx[kblk*4+fot].q[1] = *(const uint4*)(ws + off + 16);
            aw2[kblk*4+fot].q[0] = *(const uint4*)(ws + WS_W2 + off);
            aw2[kblk*4+fot].q[1] = *(const uint4*)(ws + WS_W2 + off + 16);
        }
    }

    // ---- prologue: vectors + LUT ----
    if (tid < 256) {
        ld_[tid] = ((const float*)(ws + WS_D))[tid];
        lwt[tid] = ((const float*)(ws + WS_WT))[tid];
        lb2[tid] = ((const float*)(ws + WS_B2))[tid];
        lht[tid] = ((const float*)(ws + WS_HT + n*1024))[tid];
        lh[tid]  = hmat[n*E + tid];
        float x  = fp8_to_f32(tid);
        float ax = fabsf(x);
        float em = expf(-ax);
        float sp = fmaxf(x, 0.f) + log1pf(em);
        float rr = 1.f / (1.f + em);
        float sg = (x >= 0.f) ? rr : 1.f - rr;
        union { float f; u32 u; } su; su.f = sg;
        lut[tid] = (su.u & 0xffff0000u) | (pack_fp8x4(sp, 0.f, 0.f, 0.f) & 0xffu);
    }
    __syncthreads();

    // ---- precomputed LDS addresses (rotate-swizzle: byte (f + 16*lm) & 255) ----
    unsigned char* aZ = &act[g][0][0];
    unsigned char* aS = &act[g][1][0];
    int addrB[4], addrW[4];
    #pragma unroll
    for (int kb = 0; kb < 2; ++kb)
        #pragma unroll
        for (int hf = 0; hf < 2; ++hf)
            addrB[kb*2+hf] = lm*256 + ((kb*128 + lg*32 + hf*16 + lm*16) & 255);
    #pragma unroll
    for (int ft = 0; ft < 4; ++ft)
        addrW[ft] = lm*256 + ((fbase + ft*16 + lg*4 + lm*16) & 255);

    // ---- z0 gather, log p(z0), initial z-stage ----
    const int sOwn = bId*32 + g*16 + lm;
    const int tgt  = tgts[sOwn];
    const float* z0p = emb + (size_t)tgt * E;
    f32x4 zb[4], sacc[4];
    float ssq = 0.f;
    #pragma unroll
    for (int ft = 0; ft < 4; ++ft) {
        const int f0 = fbase + ft*16 + lg*4;
        f32x4 z = *(const f32x4*)(z0p + f0);
        zb[ft] = z;
        f32x4 hv = *(const f32x4*)(lh + f0);
        #pragma unroll
        for (int r = 0; r < 4; ++r) { float dd = z[r] - hv[r]; ssq += dd*dd; }
        *(u32*)(aZ + addrW[ft]) = pack_fp8x4(z[0], z[1], z[2], z[3]);
    }
    ssq += __shfl_xor(ssq, 16);
    ssq += __shfl_xor(ssq, 32);
    if (l < 16) red[g][wg][lm] = ssq;
    __syncthreads();
    const float lp0 = -0.5f*(red[g][0][lm] + red[g][1][lm] + red[g][2][lm] + red[g][3][lm])
                      - 235.2482645f;

    const float dt = 0.125f;
    float lpacc = 0.f;

    #pragma unroll 1
    for (int e = 0; e < 32; ++e) {
        const int sub = e & 3;
        const float te = (float)(e >> 2) * dt +
                         ((sub == 0) ? 0.f : (sub == 3) ? dt : 0.5f*dt);
        // ---- mm1: pre-slice = Wx[fbase..+64, :] @ z   (MX K=128, scales=1) ----
        f32x4 acc[4];
        #pragma unroll
        for (int i = 0; i < 4; ++i) acc[i] = (f32x4){0.f,0.f,0.f,0.f};
        #pragma unroll
        for (int kb = 0; kb < 2; ++kb) {
            frag B;
            B.q[0] = *(const uint4*)(aZ + addrB[kb*2+0]);
            B.q[1] = *(const uint4*)(aZ + addrB[kb*2+1]);
            #pragma unroll
            for (int fot = 0; fot < 4; ++fot)
                acc[fot] = __builtin_amdgcn_mfma_scale_f32_16x16x128_f8f6f4(
                    awx[kb*4+fot].v, B.v, acc[fot], 0, 0, 0, SCL, 0, SCL);
        }
        // ---- activation via LUT; write sp-fp8 to aS ----
        float trp = 0.f;
        #pragma unroll
        for (int ft = 0; ft < 4; ++ft) {
            const int f0 = fbase + ft*16 + lg*4;
            f32x4 htq = *(const f32x4*)(lht + f0);
            f32x4 wtq = *(const f32x4*)(lwt + f0);
            f32x4 dq  = *(const f32x4*)(ld_ + f0);
            float p0 = acc[ft][0] + htq[0] + te*wtq[0];
            float p1 = acc[ft][1] + htq[1] + te*wtq[1];
            float p2 = acc[ft][2] + htq[2] + te*wtq[2];
            float p3 = acc[ft][3] + htq[3] + te*wtq[3];
            u32 q = pack_fp8x4(p0, p1, p2, p3);
            u32 e0 = lut[q & 255], e1 = lut[(q >> 8) & 255];
            u32 e2 = lut[(q >> 16) & 255], e3 = lut[q >> 24];
            union { u32 u; float f; } s0, s1, s2, s3;
            s0.u = e0 & 0xffff0000u; s1.u = e1 & 0xffff0000u;
            s2.u = e2 & 0xffff0000u; s3.u = e3 & 0xffff0000u;
            trp += s0.f*dq[0] + s1.f*dq[1] + s2.f*dq[2] + s3.f*dq[3];
            u32 t0 = __builtin_amdgcn_perm(e1, e0, 0x00000400u);
            u32 t1 = __builtin_amdgcn_perm(e3, e2, 0x00000400u);
            *(u32*)(aS + addrW[ft]) = __builtin_amdgcn_perm(t1, t0, 0x05040100u);
        }
        __syncthreads();                  // sp visible
        // ---- mm2: k-slice = W2[fbase..+64, :] @ softplus ----
        f32x4 acc2[4];
        #pragma unroll
        for (int i = 0; i < 4; ++i) acc2[i] = (f32x4){0.f,0.f,0.f,0.f};
        #pragma unroll
        for (int kb = 0; kb < 2; ++kb) {
            frag B;
            B.q[0] = *(const uint4*)(aS + addrB[kb*2+0]);
            B.q[1] = *(const uint4*)(aS + addrB[kb*2+1]);
            #pragma unroll
            for (int fot = 0; fot < 4; ++fot)
                acc2[fot] = __builtin_amdgcn_mfma_scale_f32_16x16x128_f8f6f4(
                    aw2[kb*4+fot].v, B.v, acc2[fot], 0, 0, 0, SCL, 0, SCL);
        }
        // ---- RK4 update; write next z-stage to aZ ----
        const float we = (sub == 0 || sub == 3) ? 1.f : 2.f;
        lpacc += we * trp;
        const float ce = (sub == 2) ? dt : 0.5f*dt;
        #pragma unroll
        for (int ft = 0; ft < 4; ++ft) {
            const int f0 = fbase + ft*16 + lg*4;
            f32x4 b2q = *(const f32x4*)(lb2 + f0);
            float z4[4];
            #pragma unroll
            for (int r = 0; r < 4; ++r) {
                float kk = acc2[ft][r] + b2q[r];
                if (sub == 0) sacc[ft][r] = kk; else sacc[ft][r] += we*kk;
                if (sub < 3) {
                    z4[r] = zb[ft][r] + ce*kk;
                } else {
                    zb[ft][r] += (dt/6.f)*sacc[ft][r];
                    z4[r] = zb[ft][r];
                }
            }
            *(u32*)(aZ + addrW[ft]) = pack_fp8x4(z4[0], z4[1], z4[2], z4[3]);
        }
        __syncthreads();                  // next z visible
    }

    // ---- final trace reduction across the 4 feature-waves ----
    lpacc += __shfl_xor(lpacc, 16);
    lpacc += __shfl_xor(lpacc, 32);
    if (l < 16) red[g][wg][lm] = lpacc;
    __syncthreads();
    if (wg == 0 && l < 16) {
        float lt = red[g][0][lm] + red[g][1][lm] + red[g][2][lm] + red[g][3][lm];
        out[sOwn] = lp0 - (dt/6.f)*lt;
    }
}

extern "C" void kernel_launch(void* const* d_in, const int* in_sizes, int n_in,
                              void* d_out, int out_size, void* d_ws, size_t ws_size,
                              hipStream_t stream) {
    const float* h    = (const float*)d_in[0];
    const float* emb  = (const float*)d_in[1];
    const int*   tg   = (const int*)d_in[2];
    const float* Wx   = (const float*)d_in[3];
    const float* wx_t = (const float*)d_in[4];
    const float* bx   = (const float*)d_in[5];
    const float* Wh   = (const float*)d_in[6];
    const float* wh_t = (const float*)d_in[7];
    const float* bh   = (const float*)d_in[8];
    const float* W2   = (const float*)d_in[9];
    const float* b2   = (const float*)d_in[10];
    unsigned char* ws = (unsigned char*)d_ws;

    prep_kernel<<<dim3(256), dim3(256), 0, stream>>>(h, Wx, wx_t, bx, Wh, wh_t, bh, W2, b2, ws);
    cnf_main<<<dim3(2048), dim3(512), 0, stream>>>(h, emb, tg, ws, (float*)d_out);
}

// Round 6
// 446.304 us; speedup vs baseline: 41.9125x; 1.1272x over previous
//
#include <hip/hip_runtime.h>

#define E 256

typedef float f32x4 __attribute__((ext_vector_type(4)));
typedef int   i32x8 __attribute__((ext_vector_type(8)));
typedef unsigned int u32;
typedef unsigned long long u64;

// ws layout (bytes):
//   [0      , 65536 )  Wx fp8 MX-A layout: [kblk(2)][lg(4)][f(256)][32B]
//   [65536  , 131072)  W2 fp8 same layout
//   [131072 , 132096)  d   (256 f32)
//   [132096 , 133120)  wt  (256 f32)
//   [133120 , 134144)  b2  (256 f32)
//   [134144 , +512KB)  ht[n][f] (512 x 256 f32) = h@Wh^T + bx + bh
#define WS_W2 65536
#define WS_D  131072
#define WS_WT 132096
#define WS_B2 133120
#define WS_HT 134144

#define SCL 0x7f7f7f7f   // E8M0 127 = 2^0 in every byte

__device__ __forceinline__ u32 pack_fp8x4(float a, float b, float c, float d) {
    int v = __builtin_amdgcn_cvt_pk_fp8_f32(a, b, 0, false);
    v = __builtin_amdgcn_cvt_pk_fp8_f32(c, d, v, true);
    return (u32)v;
}
__device__ __forceinline__ float hi_f(u32 u) { union { u32 u; float f; } x; x.u = u & 0xffff0000u; return x.f; }
__device__ __forceinline__ float lo_f(u32 u) { union { u32 u; float f; } x; x.u = u << 16; return x.f; }
__device__ __forceinline__ u32 asu(float f) { union { float f; u32 u; } x; x.f = f; return x.u; }

// decode OCP e4m3fn byte -> f32 (LUT build only; NaN clamps to +-448)
__device__ __forceinline__ float fp8_to_f32(int b) {
    int s = (b >> 7) & 1, ex = (b >> 3) & 15, mn = b & 7;
    float v;
    if (ex == 0)            v = (float)mn * 0.001953125f;
    else if (ex == 15 && mn == 7) v = 448.f;
    else                    v = (1.f + (float)mn * 0.125f) * exp2f((float)(ex - 7));
    return s ? -v : v;
}

__global__ __launch_bounds__(256) void prep_kernel(
    const float* __restrict__ h,
    const float* __restrict__ Wx, const float* __restrict__ wx_t, const float* __restrict__ bx,
    const float* __restrict__ Wh, const float* __restrict__ wh_t, const float* __restrict__ bh,
    const float* __restrict__ W2, const float* __restrict__ b2,
    unsigned char* __restrict__ ws)
{
    __shared__ float sh[2][E];
    const int b = blockIdx.x;
    const int f = threadIdx.x;
    sh[0][f] = h[(2*b)*E + f];
    sh[1][f] = h[(2*b+1)*E + f];
    __syncthreads();

    const float* whr = Wh + f*E;
    float a0 = 0.f, a1 = 0.f;
    #pragma unroll 4
    for (int i = 0; i < E; ++i) {
        float wv = whr[i];
        a0 += wv * sh[0][i];
        a1 += wv * sh[1][i];
    }
    const float bb = bx[f] + bh[f];
    float* ht = (float*)(ws + WS_HT);
    ht[(2*b)*E + f]   = a0 + bb;
    ht[(2*b+1)*E + f] = a1 + bb;

    if (b == 0) {
        const float* wxr = Wx + f*E;
        const float* w2r = W2 + f*E;
        float accd = 0.f;
        #pragma unroll 4
        for (int i = 0; i < E; ++i) accd += W2[i*E + f] * wxr[i];
        ((float*)(ws + WS_D))[f]  = accd;
        ((float*)(ws + WS_WT))[f] = wx_t[f] + wh_t[f];
        ((float*)(ws + WS_B2))[f] = b2[f];
        #pragma unroll
        for (int kblk = 0; kblk < 2; ++kblk) {
            #pragma unroll
            for (int lgb = 0; lgb < 4; ++lgb) {
                const int k0 = kblk*128 + lgb*32;
                const size_t off = (size_t)(((kblk*4 + lgb)*256) + f) * 32;
                u32 wq[8], w2q[8];
                #pragma unroll
                for (int j = 0; j < 8; ++j) {
                    f32x4 x = *(const f32x4*)(wxr + k0 + j*4);
                    wq[j]  = pack_fp8x4(x[0], x[1], x[2], x[3]);
                    x = *(const f32x4*)(w2r + k0 + j*4);
                    w2q[j] = pack_fp8x4(x[0], x[1], x[2], x[3]);
                }
                *(uint4*)(ws + off)            = *(uint4*)&wq[0];
                *(uint4*)(ws + off + 16)       = *(uint4*)&wq[4];
                *(uint4*)(ws + WS_W2 + off)    = *(uint4*)&w2q[0];
                *(uint4*)(ws + WS_W2 + off+16) = *(uint4*)&w2q[4];
            }
        }
    }
}

union frag { uint4 q[2]; i32x8 v; };

// One RK4 sub-eval, compile-time specialized on SUB (0..3).
template<int SUB>
__device__ __forceinline__ void eval_body(
    const frag (&awx)[8], const frag (&aw2)[8],
    unsigned char* aZ, unsigned char* aS,
    const int (&addrB)[4], const int (&addrW)[4],
    const u32* lut, u32* hwd, const float* lb2,
    f32x4 (&zb)[4], f32x4 (&sacc)[4], float& lpacc,
    float ht_r, float wt_r, u32 d_b, float tnext,
    int tid, int lg, int fbase)
{
    const float dt = 0.125f;
    // ---- mm1: pre = Wx @ z ----
    f32x4 acc[4];
    #pragma unroll
    for (int i = 0; i < 4; ++i) acc[i] = (f32x4){0.f,0.f,0.f,0.f};
    __builtin_amdgcn_s_setprio(1);
    #pragma unroll
    for (int kb = 0; kb < 2; ++kb) {
        frag B;
        B.q[0] = *(const uint4*)(aZ + addrB[kb*2+0]);
        B.q[1] = *(const uint4*)(aZ + addrB[kb*2+1]);
        #pragma unroll
        for (int fot = 0; fot < 4; ++fot)
            acc[fot] = __builtin_amdgcn_mfma_scale_f32_16x16x128_f8f6f4(
                awx[kb*4+fot].v, B.v, acc[fot], 0, 0, 0, SCL, 0, SCL);
    }
    __builtin_amdgcn_s_setprio(0);
    // ---- activation: x = acc + hw; LUT -> {sg, sp}; trace ----
    float trp = 0.f;
    #pragma unroll
    for (int ft = 0; ft < 4; ++ft) {
        const int f0 = fbase + ft*16 + lg*4;
        uint4 hq = *(const uint4*)(hwd + f0);             // broadcast read
        float x0 = acc[ft][0] + hi_f(hq.x);
        float x1 = acc[ft][1] + hi_f(hq.y);
        float x2 = acc[ft][2] + hi_f(hq.z);
        float x3 = acc[ft][3] + hi_f(hq.w);
        u32 q  = pack_fp8x4(x0, x1, x2, x3);
        u32 e0 = lut[q & 255],        e1 = lut[(q >> 8) & 255];
        u32 e2 = lut[(q >> 16) & 255], e3 = lut[q >> 24];
        trp += hi_f(e0)*lo_f(hq.x) + hi_f(e1)*lo_f(hq.y)
             + hi_f(e2)*lo_f(hq.z) + hi_f(e3)*lo_f(hq.w);
        u32 t0_ = __builtin_amdgcn_perm(e1, e0, 0x00000400u);
        u32 t1_ = __builtin_amdgcn_perm(e3, e2, 0x00000400u);
        *(u32*)(aS + addrW[ft]) = __builtin_amdgcn_perm(t1_, t0_, 0x05040100u);
    }
    __syncthreads();                 // sp visible
    // ---- mm2: k = W2 @ softplus ----
    f32x4 acc2[4];
    #pragma unroll
    for (int i = 0; i < 4; ++i) acc2[i] = (f32x4){0.f,0.f,0.f,0.f};
    __builtin_amdgcn_s_setprio(1);
    #pragma unroll
    for (int kb = 0; kb < 2; ++kb) {
        frag B;
        B.q[0] = *(const uint4*)(aS + addrB[kb*2+0]);
        B.q[1] = *(const uint4*)(aS + addrB[kb*2+1]);
        #pragma unroll
        for (int fot = 0; fot < 4; ++fot)
            acc2[fot] = __builtin_amdgcn_mfma_scale_f32_16x16x128_f8f6f4(
                aw2[kb*4+fot].v, B.v, acc2[fot], 0, 0, 0, SCL, 0, SCL);
    }
    __builtin_amdgcn_s_setprio(0);
    // ---- RK4 update (fully specialized) ----
    const float we = (SUB == 0 || SUB == 3) ? 1.f : 2.f;
    lpacc += we * trp;
    #pragma unroll
    for (int ft = 0; ft < 4; ++ft) {
        const int f0 = fbase + ft*16 + lg*4;
        f32x4 b2q = *(const f32x4*)(lb2 + f0);            // broadcast read
        float z4[4];
        #pragma unroll
        for (int r = 0; r < 4; ++r) {
            float kk = acc2[ft][r] + b2q[r];
            if (SUB == 0) sacc[ft][r] = kk;
            else          sacc[ft][r] += we * kk;
            if (SUB < 3) {
                const float ce = (SUB == 2) ? dt : 0.0625f;
                z4[r] = zb[ft][r] + ce * kk;
            } else {
                zb[ft][r] += (dt/6.f) * sacc[ft][r];
                z4[r] = zb[ft][r];
            }
        }
        *(u32*)(aZ + addrW[ft]) = pack_fp8x4(z4[0], z4[1], z4[2], z4[3]);
    }
    // ---- hw update for the next te (only at te transitions) ----
    if (SUB == 0 || SUB == 2) {
        float hwv = fmaf(tnext, wt_r, ht_r);
        hwd[tid] = ((asu(hwv) + 0x8000u) & 0xffff0000u) | d_b;
    }
    __syncthreads();                 // next z (and hw) visible
}

// 4096 blocks x 256 thr; 1 group of 16 samples; wave wv owns features [wv*64,+64).
// 2 blocks/CU co-resident with independent barriers -> cross-block pipe overlap.
__global__ __launch_bounds__(256, 2) void cnf_main(
    const float* __restrict__ hmat, const float* __restrict__ emb,
    const int* __restrict__ tgts, const unsigned char* __restrict__ ws,
    float* __restrict__ out)
{
    __shared__ __align__(16) unsigned char act[2][4096];  // [z/sp][16 rows x 256B, rotated]
    __shared__ __align__(16) u32 lut[256];                // sg_bf16<<16 | sp_fp8
    __shared__ __align__(16) u32 hwd[256];                // hw_bf16<<16 | d_bf16
    __shared__ __align__(16) float lb2[E];
    __shared__ float red_s[4][16], red_t[4][16];

    const int tid = threadIdx.x;
    const int bId = blockIdx.x;
    const int n   = bId >> 3;               // 8 blocks per h-row
    const int l   = tid & 63, wv = tid >> 6;
    const int lm  = l & 15,  lg = l >> 4;
    const int fbase = wv * 64;

    // ---- weight fragments -> registers ----
    frag awx[8], aw2[8];
    #pragma unroll
    for (int kblk = 0; kblk < 2; ++kblk) {
        #pragma unroll
        for (int fot = 0; fot < 4; ++fot) {
            const size_t off = (size_t)(((kblk*4 + lg)*256) + fbase + fot*16 + lm) * 32;
            awx[kblk*4+fot].q[0] = *(const uint4*)(ws + off);
            awx[kblk*4+fot].q[1] = *(const uint4*)(ws + off + 16);
            aw2[kblk*4+fot].q[0] = *(const uint4*)(ws + WS_W2 + off);
            aw2[kblk*4+fot].q[1] = *(const uint4*)(ws + WS_W2 + off + 16);
        }
    }

    // ---- per-thread params (feature f = tid) ----
    const float ht_r = ((const float*)(ws + WS_HT))[n*E + tid];
    const float wt_r = ((const float*)(ws + WS_WT))[tid];
    const float d_f  = ((const float*)(ws + WS_D))[tid];
    const u32   d_b  = (asu(d_f) + 0x8000u) >> 16;
    lb2[tid] = ((const float*)(ws + WS_B2))[tid];
    {   // LUT entry for fp8 byte = tid
        float x  = fp8_to_f32(tid);
        float ax = fabsf(x);
        float em = expf(-ax);
        float sp = fmaxf(x, 0.f) + log1pf(em);
        float rr = 1.f / (1.f + em);
        float sg = (x >= 0.f) ? rr : 1.f - rr;
        lut[tid] = (asu(sg) & 0xffff0000u) | (pack_fp8x4(sp, 0.f, 0.f, 0.f) & 0xffu);
    }
    hwd[tid] = ((asu(ht_r) + 0x8000u) & 0xffff0000u) | d_b;   // te = 0

    // ---- LDS addresses (rotate-swizzle: byte (f + 16*lm) & 255) ----
    unsigned char* aZ = &act[0][0];
    unsigned char* aS = &act[1][0];
    int addrB[4], addrW[4];
    #pragma unroll
    for (int kb = 0; kb < 2; ++kb)
        #pragma unroll
        for (int hf = 0; hf < 2; ++hf)
            addrB[kb*2+hf] = lm*256 + ((kb*128 + lg*32 + hf*16 + lm*16) & 255);
    #pragma unroll
    for (int ft = 0; ft < 4; ++ft)
        addrW[ft] = lm*256 + ((fbase + ft*16 + lg*4 + lm*16) & 255);

    // ---- z0 gather, log p(z0) partial, initial z-stage ----
    const int sOwn = bId*16 + lm;
    const int tgt  = tgts[sOwn];
    const float* z0p = emb + (size_t)tgt * E;
    f32x4 zb[4], sacc[4];
    float ssq = 0.f;
    #pragma unroll
    for (int ft = 0; ft < 4; ++ft) {
        const int f0 = fbase + ft*16 + lg*4;
        f32x4 z = *(const f32x4*)(z0p + f0);
        zb[ft] = z;
        f32x4 hv = *(const f32x4*)(hmat + n*E + f0);
        #pragma unroll
        for (int r = 0; r < 4; ++r) { float dd = z[r] - hv[r]; ssq += dd*dd; }
        *(u32*)(aZ + addrW[ft]) = pack_fp8x4(z[0], z[1], z[2], z[3]);
    }
    ssq += __shfl_xor(ssq, 16);
    ssq += __shfl_xor(ssq, 32);
    if (l < 16) red_s[wv][lm] = ssq;
    __syncthreads();

    const float dt = 0.125f;
    float lpacc = 0.f;

    #pragma unroll 1
    for (int st = 0; st < 8; ++st) {
        const float t0 = st * dt;
        eval_body<0>(awx, aw2, aZ, aS, addrB, addrW, lut, hwd, lb2,
                     zb, sacc, lpacc, ht_r, wt_r, d_b, t0 + 0.0625f, tid, lg, fbase);
        eval_body<1>(awx, aw2, aZ, aS, addrB, addrW, lut, hwd, lb2,
                     zb, sacc, lpacc, ht_r, wt_r, d_b, 0.f, tid, lg, fbase);
        eval_body<2>(awx, aw2, aZ, aS, addrB, addrW, lut, hwd, lb2,
                     zb, sacc, lpacc, ht_r, wt_r, d_b, t0 + 0.125f, tid, lg, fbase);
        eval_body<3>(awx, aw2, aZ, aS, addrB, addrW, lut, hwd, lb2,
                     zb, sacc, lpacc, ht_r, wt_r, d_b, 0.f, tid, lg, fbase);
    }

    // ---- final trace reduction across the 4 feature-waves ----
    lpacc += __shfl_xor(lpacc, 16);
    lpacc += __shfl_xor(lpacc, 32);
    if (l < 16) red_t[wv][lm] = lpacc;
    __syncthreads();
    if (wv == 0 && l < 16) {
        float ss = red_s[0][lm] + red_s[1][lm] + red_s[2][lm] + red_s[3][lm];
        float lt = red_t[0][lm] + red_t[1][lm] + red_t[2][lm] + red_t[3][lm];
        out[sOwn] = -0.5f*ss - 235.2482645f - (dt/6.f)*lt;
    }
}

extern "C" void kernel_launch(void* const* d_in, const int* in_sizes, int n_in,
                              void* d_out, int out_size, void* d_ws, size_t ws_size,
                              hipStream_t stream) {
    const float* h    = (const float*)d_in[0];
    const float* emb  = (const float*)d_in[1];
    const int*   tg   = (const int*)d_in[2];
    const float* Wx   = (const float*)d_in[3];
    const float* wx_t = (const float*)d_in[4];
    const float* bx   = (const float*)d_in[5];
    const float* Wh   = (const float*)d_in[6];
    const float* wh_t = (const float*)d_in[7];
    const float* bh   = (const float*)d_in[8];
    const float* W2   = (const float*)d_in[9];
    const float* b2   = (const float*)d_in[10];
    unsigned char* ws = (unsigned char*)d_ws;

    prep_kernel<<<dim3(256), dim3(256), 0, stream>>>(h, Wx, wx_t, bx, Wh, wh_t, bh, W2, b2, ws);
    cnf_main<<<dim3(4096), dim3(256), 0, stream>>>(h, emb, tg, ws, (float*)d_out);
}

// Round 7
// 379.633 us; speedup vs baseline: 49.2732x; 1.1756x over previous
//
#include <hip/hip_runtime.h>

#define E 256

typedef float f32x4 __attribute__((ext_vector_type(4)));
typedef int   i32x8 __attribute__((ext_vector_type(8)));
typedef unsigned int u32;
typedef unsigned long long u64;

// ws layout (bytes):
//   [0      , 65536 )  Wx fp8 MX-A layout: [kblk(2)][lg(4)][f(256)][32B]
//   [65536  , 131072)  W2 fp8 same layout
//   [131072 , 131328)  d_fp8 (256 bytes)  d[f] = sum_i W2[i][f]*Wx[f][i]
//   [132096 , 133120)  wt  (256 f32)
//   [133120 , 134144)  b2  (256 f32)
//   [134144 , +512KB)  ht[n][f] (512 x 256 f32) = h@Wh^T + bx + bh
#define WS_W2 65536
#define WS_D  131072
#define WS_WT 132096
#define WS_B2 133120
#define WS_HT 134144

#define SCL 0x7f7f7f7f   // E8M0 127 = 2^0 in every byte

__device__ __forceinline__ u32 pack_fp8x4(float a, float b, float c, float d) {
    int v = __builtin_amdgcn_cvt_pk_fp8_f32(a, b, 0, false);
    v = __builtin_amdgcn_cvt_pk_fp8_f32(c, d, v, true);
    return (u32)v;
}
__device__ __forceinline__ u32 asu(float f) { union { float f; u32 u; } x; x.f = f; return x.u; }

// decode OCP e4m3fn byte -> f32 (LUT build only; NaN clamps to +-448)
__device__ __forceinline__ float fp8_to_f32(int b) {
    int s = (b >> 7) & 1, ex = (b >> 3) & 15, mn = b & 7;
    float v;
    if (ex == 0)            v = (float)mn * 0.001953125f;
    else if (ex == 15 && mn == 7) v = 448.f;
    else                    v = (1.f + (float)mn * 0.125f) * exp2f((float)(ex - 7));
    return s ? -v : v;
}

__global__ __launch_bounds__(256) void prep_kernel(
    const float* __restrict__ h,
    const float* __restrict__ Wx, const float* __restrict__ wx_t, const float* __restrict__ bx,
    const float* __restrict__ Wh, const float* __restrict__ wh_t, const float* __restrict__ bh,
    const float* __restrict__ W2, const float* __restrict__ b2,
    unsigned char* __restrict__ ws)
{
    __shared__ float sh[2][E];
    const int b = blockIdx.x;
    const int f = threadIdx.x;
    sh[0][f] = h[(2*b)*E + f];
    sh[1][f] = h[(2*b+1)*E + f];
    __syncthreads();

    const float* whr = Wh + f*E;
    float a0 = 0.f, a1 = 0.f;
    #pragma unroll 4
    for (int i = 0; i < E; ++i) {
        float wv = whr[i];
        a0 += wv * sh[0][i];
        a1 += wv * sh[1][i];
    }
    const float bb = bx[f] + bh[f];
    float* ht = (float*)(ws + WS_HT);
    ht[(2*b)*E + f]   = a0 + bb;
    ht[(2*b+1)*E + f] = a1 + bb;

    if (b == 0) {
        const float* wxr = Wx + f*E;
        const float* w2r = W2 + f*E;
        float accd = 0.f;
        #pragma unroll 4
        for (int i = 0; i < E; ++i) accd += W2[i*E + f] * wxr[i];
        ws[WS_D + f] = (unsigned char)(pack_fp8x4(accd, 0.f, 0.f, 0.f) & 255u);
        ((float*)(ws + WS_WT))[f] = wx_t[f] + wh_t[f];
        ((float*)(ws + WS_B2))[f] = b2[f];
        #pragma unroll
        for (int kblk = 0; kblk < 2; ++kblk) {
            #pragma unroll
            for (int lgb = 0; lgb < 4; ++lgb) {
                const int k0 = kblk*128 + lgb*32;
                const size_t off = (size_t)(((kblk*4 + lgb)*256) + f) * 32;
                u32 wq[8], w2q[8];
                #pragma unroll
                for (int j = 0; j < 8; ++j) {
                    f32x4 x = *(const f32x4*)(wxr + k0 + j*4);
                    wq[j]  = pack_fp8x4(x[0], x[1], x[2], x[3]);
                    x = *(const f32x4*)(w2r + k0 + j*4);
                    w2q[j] = pack_fp8x4(x[0], x[1], x[2], x[3]);
                }
                *(uint4*)(ws + off)            = *(uint4*)&wq[0];
                *(uint4*)(ws + off + 16)       = *(uint4*)&wq[4];
                *(uint4*)(ws + WS_W2 + off)    = *(uint4*)&w2q[0];
                *(uint4*)(ws + WS_W2 + off+16) = *(uint4*)&w2q[4];
            }
        }
    }
}

union frag { uint4 q[2]; i32x8 v; };

// One RK4 sub-eval, compile-time specialized on SUB (0..3).
template<int SUB>
__device__ __forceinline__ void eval_body(
    const frag (&awx)[8], const frag (&aw2)[8],
    unsigned char* aZ, unsigned char* aS, unsigned char* aG,
    const int (&addrB)[4], const int (&addrW)[4],
    const u32* lutb, float* hwf, const float* lb2f,
    const unsigned char* dfp8,
    f32x4 (&zb)[4], f32x4 (&sacc)[4], f32x4& ctr,
    float ht_r, float wt_r, float tnext,
    int tid, int wv, int lg, int fbase)
{
    const float dt = 0.125f;
    // ---- mm1: pre = Wx @ z + hw  (hw folded in as C-init, f32) ----
    f32x4 acc[4];
    #pragma unroll
    for (int ft = 0; ft < 4; ++ft)
        acc[ft] = *(const f32x4*)(hwf + fbase + ft*16 + lg*4);   // broadcast b128
    __builtin_amdgcn_s_setprio(1);
    #pragma unroll
    for (int kb = 0; kb < 2; ++kb) {
        frag B;
        B.q[0] = *(const uint4*)(aZ + addrB[kb*2+0]);
        B.q[1] = *(const uint4*)(aZ + addrB[kb*2+1]);
        #pragma unroll
        for (int fot = 0; fot < 4; ++fot)
            acc[fot] = __builtin_amdgcn_mfma_scale_f32_16x16x128_f8f6f4(
                awx[kb*4+fot].v, B.v, acc[fot], 0, 0, 0, SCL, 0, SCL);
    }
    __builtin_amdgcn_s_setprio(0);
    // ---- act: conflict-free LUT gather -> {sp, sg} fp8 quads -> LDS ----
    #pragma unroll
    for (int ft = 0; ft < 4; ++ft) {
        u32 q  = pack_fp8x4(acc[ft][0], acc[ft][1], acc[ft][2], acc[ft][3]);
        u32 e0 = lutb[(q & 255u) << 5];
        u32 e1 = lutb[((q >> 8) & 255u) << 5];
        u32 e2 = lutb[((q >> 16) & 255u) << 5];
        u32 e3 = lutb[(q >> 24) << 5];
        u32 t0 = __builtin_amdgcn_perm(e1, e0, 0x05040100u);   // {sp0,sg0,sp1,sg1}
        u32 t1 = __builtin_amdgcn_perm(e3, e2, 0x05040100u);
        *(u32*)(aS + addrW[ft]) = __builtin_amdgcn_perm(t1, t0, 0x06040200u); // sp quad
        *(u32*)(aG + addrW[ft]) = __builtin_amdgcn_perm(t1, t0, 0x07050301u); // sg quad
    }
    __syncthreads();                 // sp/sg visible
    // ---- mm2: k = W2 @ softplus + b2 (b2 as C-init) ----
    f32x4 acc2[4];
    #pragma unroll
    for (int ft = 0; ft < 4; ++ft)
        acc2[ft] = *(const f32x4*)(lb2f + fbase + ft*16 + lg*4);
    __builtin_amdgcn_s_setprio(1);
    #pragma unroll
    for (int kb = 0; kb < 2; ++kb) {
        frag B;
        B.q[0] = *(const uint4*)(aS + addrB[kb*2+0]);
        B.q[1] = *(const uint4*)(aS + addrB[kb*2+1]);
        #pragma unroll
        for (int fot = 0; fot < 4; ++fot)
            acc2[fot] = __builtin_amdgcn_mfma_scale_f32_16x16x128_f8f6f4(
                aw2[kb*4+fot].v, B.v, acc2[fot], 0, 0, 0, SCL, 0, SCL);
    }
    __builtin_amdgcn_s_setprio(0);
    // ---- trace MFMA (wave 0 only): ctr += d * sg, RK4 weight in B-scale ----
    if (wv == 0) {
        const u32 wescl = (SUB == 1 || SUB == 2) ? 0x80808080u : 0x7f7f7f7fu; // x2 / x1
        #pragma unroll
        for (int kb = 0; kb < 2; ++kb) {
            frag Bg, Ad;
            Bg.q[0] = *(const uint4*)(aG + addrB[kb*2+0]);
            Bg.q[1] = *(const uint4*)(aG + addrB[kb*2+1]);
            Ad.q[0] = *(const uint4*)(dfp8 + kb*128 + lg*32);      // row-replicated d
            Ad.q[1] = *(const uint4*)(dfp8 + kb*128 + lg*32 + 16);
            ctr = __builtin_amdgcn_mfma_scale_f32_16x16x128_f8f6f4(
                Ad.v, Bg.v, ctr, 0, 0, 0, SCL, 0, wescl);
        }
    }
    // ---- RK4 update (kk = acc2 directly, b2 already included) ----
    const float we = (SUB == 0 || SUB == 3) ? 1.f : 2.f;
    #pragma unroll
    for (int ft = 0; ft < 4; ++ft) {
        float z4[4];
        #pragma unroll
        for (int r = 0; r < 4; ++r) {
            float kk = acc2[ft][r];
            if (SUB == 0) sacc[ft][r] = kk;
            else          sacc[ft][r] += we * kk;
            if (SUB < 3) {
                const float ce = (SUB == 2) ? dt : 0.0625f;
                z4[r] = zb[ft][r] + ce * kk;
            } else {
                zb[ft][r] += (dt/6.f) * sacc[ft][r];
                z4[r] = zb[ft][r];
            }
        }
        *(u32*)(aZ + addrW[ft]) = pack_fp8x4(z4[0], z4[1], z4[2], z4[3]);
    }
    // ---- hw := ht + tnext*wt for the next te (te transitions only) ----
    if (SUB == 0 || SUB == 2) hwf[tid] = fmaf(tnext, wt_r, ht_r);
    __syncthreads();                 // next z (and hw) visible
}

// 4096 blocks x 256 thr; 16 samples/block; wave wv owns features [wv*64,+64).
// 2 blocks/CU co-resident, independent barriers -> cross-block pipe overlap.
__global__ __launch_bounds__(256, 2) void cnf_main(
    const float* __restrict__ hmat, const float* __restrict__ emb,
    const int* __restrict__ tgts, const unsigned char* __restrict__ ws,
    float* __restrict__ out)
{
    __shared__ __align__(16) u32 lut[256*32];             // bank-replicated {sg,sp}
    __shared__ __align__(16) unsigned char aZ[4096];      // z fp8, rotated
    __shared__ __align__(16) unsigned char aS[4096];      // softplus fp8
    __shared__ __align__(16) unsigned char aG[4096];      // sigmoid fp8
    __shared__ __align__(16) float hwf[E];                // ht + te*wt (f32)
    __shared__ __align__(16) float lb2f[E];
    __shared__ __align__(16) unsigned char dfp8[E];
    __shared__ float red_s[4][16];

    const int tid = threadIdx.x;
    const int bId = blockIdx.x;
    const int n   = bId >> 3;               // 8 blocks per h-row
    const int l   = tid & 63, wv = tid >> 6;
    const int lm  = l & 15,  lg = l >> 4;
    const int fbase = wv * 64;

    // ---- weight fragments -> registers ----
    frag awx[8], aw2[8];
    #pragma unroll
    for (int kblk = 0; kblk < 2; ++kblk) {
        #pragma unroll
        for (int fot = 0; fot < 4; ++fot) {
            const size_t off = (size_t)(((kblk*4 + lg)*256) + fbase + fot*16 + lm) * 32;
            awx[kblk*4+fot].q[0] = *(const uint4*)(ws + off);
            awx[kblk*4+fot].q[1] = *(const uint4*)(ws + off + 16);
            aw2[kblk*4+fot].q[0] = *(const uint4*)(ws + WS_W2 + off);
            aw2[kblk*4+fot].q[1] = *(const uint4*)(ws + WS_W2 + off + 16);
        }
    }

    // ---- per-thread params + LDS init ----
    const float ht_r = ((const float*)(ws + WS_HT))[n*E + tid];
    const float wt_r = ((const float*)(ws + WS_WT))[tid];
    hwf[tid]  = ht_r;                       // te = 0
    lb2f[tid] = ((const float*)(ws + WS_B2))[tid];
    dfp8[tid] = ws[WS_D + tid];
    {   // LUT entry for fp8 byte = tid: byte0 = sp_fp8, byte1 = sg_fp8
        float x  = fp8_to_f32(tid);
        float ax = fabsf(x);
        float em = expf(-ax);
        float sp = fmaxf(x, 0.f) + log1pf(em);
        float rr = 1.f / (1.f + em);
        float sg = (x >= 0.f) ? rr : 1.f - rr;
        u32 entry = ((pack_fp8x4(sg, 0.f, 0.f, 0.f) & 255u) << 8)
                  |  (pack_fp8x4(sp, 0.f, 0.f, 0.f) & 255u);
        #pragma unroll
        for (int bk = 0; bk < 32; ++bk) lut[tid*32 + bk] = entry;
    }
    const u32* lutb = lut + (l & 31);       // own-bank base -> conflict-free gathers

    // ---- LDS addresses (rotate-swizzle: byte (f + 16*lm) & 255) ----
    int addrB[4], addrW[4];
    #pragma unroll
    for (int kb = 0; kb < 2; ++kb)
        #pragma unroll
        for (int hf = 0; hf < 2; ++hf)
            addrB[kb*2+hf] = lm*256 + ((kb*128 + lg*32 + hf*16 + lm*16) & 255);
    #pragma unroll
    for (int ft = 0; ft < 4; ++ft)
        addrW[ft] = lm*256 + ((fbase + ft*16 + lg*4 + lm*16) & 255);

    // ---- z0 gather, log p(z0) partial, initial z-stage ----
    const int sOwn = bId*16 + lm;
    const int tgt  = tgts[sOwn];
    const float* z0p = emb + (size_t)tgt * E;
    f32x4 zb[4], sacc[4];
    f32x4 ctr = (f32x4){0.f, 0.f, 0.f, 0.f};
    float ssq = 0.f;
    #pragma unroll
    for (int ft = 0; ft < 4; ++ft) {
        const int f0 = fbase + ft*16 + lg*4;
        f32x4 z = *(const f32x4*)(z0p + f0);
        zb[ft] = z;
        f32x4 hv = *(const f32x4*)(hmat + n*E + f0);
        #pragma unroll
        for (int r = 0; r < 4; ++r) { float dd = z[r] - hv[r]; ssq += dd*dd; }
        *(u32*)(aZ + addrW[ft]) = pack_fp8x4(z[0], z[1], z[2], z[3]);
    }
    ssq += __shfl_xor(ssq, 16);
    ssq += __shfl_xor(ssq, 32);
    if (l < 16) red_s[wv][lm] = ssq;
    __syncthreads();

    const float dt = 0.125f;
    #pragma unroll 1
    for (int st = 0; st < 8; ++st) {
        const float t0 = st * dt;
        eval_body<0>(awx, aw2, aZ, aS, aG, addrB, addrW, lutb, hwf, lb2f, dfp8,
                     zb, sacc, ctr, ht_r, wt_r, t0 + 0.0625f, tid, wv, lg, fbase);
        eval_body<1>(awx, aw2, aZ, aS, aG, addrB, addrW, lutb, hwf, lb2f, dfp8,
                     zb, sacc, ctr, ht_r, wt_r, 0.f, tid, wv, lg, fbase);
        eval_body<2>(awx, aw2, aZ, aS, aG, addrB, addrW, lutb, hwf, lb2f, dfp8,
                     zb, sacc, ctr, ht_r, wt_r, t0 + 0.125f, tid, wv, lg, fbase);
        eval_body<3>(awx, aw2, aZ, aS, aG, addrB, addrW, lutb, hwf, lb2f, dfp8,
                     zb, sacc, ctr, ht_r, wt_r, 0.f, tid, wv, lg, fbase);
    }

    // ---- output: wave 0 lanes 0-15 hold tr[lm] in ctr (rows replicated) ----
    if (wv == 0 && l < 16) {
        float ss = red_s[0][lm] + red_s[1][lm] + red_s[2][lm] + red_s[3][lm];
        out[sOwn] = -0.5f*ss - 235.2482645f - (dt/6.f)*ctr[0];
    }
}

extern "C" void kernel_launch(void* const* d_in, const int* in_sizes, int n_in,
                              void* d_out, int out_size, void* d_ws, size_t ws_size,
                              hipStream_t stream) {
    const float* h    = (const float*)d_in[0];
    const float* emb  = (const float*)d_in[1];
    const int*   tg   = (const int*)d_in[2];
    const float* Wx   = (const float*)d_in[3];
    const float* wx_t = (const float*)d_in[4];
    const float* bx   = (const float*)d_in[5];
    const float* Wh   = (const float*)d_in[6];
    const float* wh_t = (const float*)d_in[7];
    const float* bh   = (const float*)d_in[8];
    const float* W2   = (const float*)d_in[9];
    const float* b2   = (const float*)d_in[10];
    unsigned char* ws = (unsigned char*)d_ws;

    prep_kernel<<<dim3(256), dim3(256), 0, stream>>>(h, Wx, wx_t, bx, Wh, wh_t, bh, W2, b2, ws);
    cnf_main<<<dim3(4096), dim3(256), 0, stream>>>(h, emb, tg, ws, (float*)d_out);
}